// Round 14
// baseline (89.255 us; speedup 1.0000x reference)
//
#include <hip/hip_runtime.h>
#include <hip/hip_bf16.h>

typedef __attribute__((ext_vector_type(8))) short short8;
typedef __attribute__((ext_vector_type(4))) float f32x4;
typedef __attribute__((ext_vector_type(2))) unsigned uint2v;

#define MFMA16(a, b, c) __builtin_amdgcn_mfma_f32_16x16x32_bf16((a), (b), (c), 0, 0, 0)

constexpr int Bc = 2, Lc = 2048, Hc = 16, Ec = 64;
constexpr float LOG2E = 1.4426950408889634f;
constexpr float SCALE2 = 0.125f * LOG2E;   // fold log2(e): scores in log2 units
constexpr float NEGBIG = -3.0e38f;

union SW { short8 s8; unsigned u[4]; float4 f4; };

__device__ __forceinline__ unsigned cvtpk(float lo, float hi) {
  unsigned r;
  asm("v_cvt_pk_bf16_f32 %0, %1, %2" : "=v"(r) : "v"(lo), "v"(hi));
  return r;
}
__device__ __forceinline__ float exp2v(float x) {
  float r;
  asm("v_exp_f32 %0, %1" : "=v"(r) : "v"(x));
  return r;
}
__device__ __forceinline__ float bfhi(unsigned u) {
  return __builtin_bit_cast(float, u & 0xffff0000u);
}
__device__ __forceinline__ float bflo(unsigned u) {
  return __builtin_bit_cast(float, u << 16);
}
// SSA builtins: no register-aliasing hazard
__device__ __forceinline__ void plswap32(unsigned& a, unsigned& b) {
  uint2v r = __builtin_amdgcn_permlane32_swap(a, b, false, false);
  a = r[0]; b = r[1];
}
__device__ __forceinline__ void plswap16(unsigned& a, unsigned& b) {
  uint2v r = __builtin_amdgcn_permlane16_swap(a, b, false, false);
  a = r[0]; b = r[1];
}
// butterfly max over lanes {l, l^16, l^32, l^48}, pure VALU
__device__ __forceinline__ float bflymax(float x) {
  unsigned a = __builtin_bit_cast(unsigned, x), b = a;
  plswap16(a, b);
  float y = fmaxf(__builtin_bit_cast(float, a), __builtin_bit_cast(float, b));
  a = __builtin_bit_cast(unsigned, y); b = a;
  plswap32(a, b);
  return fmaxf(__builtin_bit_cast(float, a), __builtin_bit_cast(float, b));
}
__device__ __forceinline__ float bflysum(float x) {
  unsigned a = __builtin_bit_cast(unsigned, x), b = a;
  plswap16(a, b);
  float y = __builtin_bit_cast(float, a) + __builtin_bit_cast(float, b);
  a = __builtin_bit_cast(unsigned, y); b = a;
  plswap32(a, b);
  return __builtin_bit_cast(float, a) + __builtin_bit_cast(float, b);
}

__global__ __launch_bounds__(512, 2)
void attn_fwd(const float* __restrict__ Qg, const float* __restrict__ Kg,
              const float* __restrict__ Vg, float* __restrict__ Og) {
  // smem (shorts), NT=128 s-tile double-buffered:
  //  kt[b]: [128][64] bf16 at b*8192, K row s at prow=pi(s) (bits2<->3),
  //         idx ^ ((prow&7)<<3)
  //  vt[b]: [64 e][128 s] bf16 at 16384 + b*8192, chunk slot = (s>>3) ^ (e&7)
  // merge scratch overlays the RETIRED buffer.
  __shared__ __align__(16) short smem[32768];

  // causal fold: block owns q-tile pair (i, 31-i): exactly 17 uniform rounds
  const int bid = blockIdx.x;
  const int pair = bid & 15;
  const int bh = bid >> 4;
  const int h = bh & (Hc - 1);
  const int b = bh >> 4;
  const int iLo = pair;
  const int QbL = iLo * 64;
  const int QbH = (31 - pair) * 64;
  const int RL = (iLo + 2) >> 1;              // lo-tile rounds; RL + RH = 17

  const int t = threadIdx.x;
  const int w = t >> 6;        // 0..7
  const int qsub = w & 3;      // q sub-block (16 rows)
  const int par = w >> 2;      // 64-s half of the 128-row tile
  const int l = t & 63;
  const int n = l & 15;
  const int g = l >> 4;
  const int sp4 = ((g & 1) << 3) | ((g >> 1) << 2);  // pi(g)*4

  const f32x4 zero4 = {0.f, 0.f, 0.f, 0.f};

  // Q fragments (B-operand: col=q=lane&15, k=e=(lane>>4)*8+j)
  short8 qf[2];
  auto loadq = [&](int Qb) {
    const int q = Qb + qsub * 16 + n;
    const float* qp = Qg + ((size_t)(b * Lc + q) * Hc + h) * Ec + g * 8;
    SW a0, a1, b0, b1, r0, r1;
    a0.f4 = reinterpret_cast<const float4*>(qp)[0];
    a1.f4 = reinterpret_cast<const float4*>(qp)[1];
    b0.f4 = reinterpret_cast<const float4*>(qp + 32)[0];
    b1.f4 = reinterpret_cast<const float4*>(qp + 32)[1];
    r0.u[0] = cvtpk(a0.f4.x * SCALE2, a0.f4.y * SCALE2);
    r0.u[1] = cvtpk(a0.f4.z * SCALE2, a0.f4.w * SCALE2);
    r0.u[2] = cvtpk(a1.f4.x * SCALE2, a1.f4.y * SCALE2);
    r0.u[3] = cvtpk(a1.f4.z * SCALE2, a1.f4.w * SCALE2);
    r1.u[0] = cvtpk(b0.f4.x * SCALE2, b0.f4.y * SCALE2);
    r1.u[1] = cvtpk(b0.f4.z * SCALE2, b0.f4.w * SCALE2);
    r1.u[2] = cvtpk(b1.f4.x * SCALE2, b1.f4.y * SCALE2);
    r1.u[3] = cvtpk(b1.f4.z * SCALE2, b1.f4.w * SCALE2);
    qf[0] = r0.s8;
    qf[1] = r1.s8;
  };

  // acc[e4][r] = O^T[e = e4*16 + g*4 + r][q = n]; per-lane scalar m,l
  f32x4 acc[4] = {zero4, zero4, zero4, zero4};
  float mrun = NEGBIG, lrun = 0.f;

  // staging: 512 threads stage 128 rows of K (pi-permuted) and V^T per round
  const int srow = t >> 2;                               // 0..127
  const int prow = (srow & ~12) | ((srow & 4) << 1) | ((srow & 8) >> 1);
  const int kc0 = (t & 3) * 16;                          // 16-float column chunk
  const int ve = l, vs0 = w * 16;                        // V^T: e=lane, 16 s rows

  float4 ka[4];
  float va[16];

  // Forced-async stage: volatile asm loads issue HERE (unsinkable), results
  // waited in commit() after the round's compute has covered the latency.
  auto issue = [&](int r0) {
    unsigned koff = (unsigned)((((b * Lc + r0 + srow) * Hc + h) * Ec + kc0) * 4);
    unsigned voff = (unsigned)((((b * Lc + r0 + vs0) * Hc + h) * Ec + ve) * 4);
    asm volatile(
      "global_load_dwordx4 %[k0], %[ko], %[kb]\n\t"
      "global_load_dwordx4 %[k1], %[ko], %[kb] offset:16\n\t"
      "global_load_dwordx4 %[k2], %[ko], %[kb] offset:32\n\t"
      "global_load_dwordx4 %[k3], %[ko], %[kb] offset:48\n\t"
      "global_load_dword %[v0], %[vo], %[vb]\n\t"
      "v_add_u32 %[vo], 0x1000, %[vo]\n\t"
      "global_load_dword %[v1], %[vo], %[vb]\n\t"
      "v_add_u32 %[vo], 0x1000, %[vo]\n\t"
      "global_load_dword %[v2], %[vo], %[vb]\n\t"
      "v_add_u32 %[vo], 0x1000, %[vo]\n\t"
      "global_load_dword %[v3], %[vo], %[vb]\n\t"
      "v_add_u32 %[vo], 0x1000, %[vo]\n\t"
      "global_load_dword %[v4], %[vo], %[vb]\n\t"
      "v_add_u32 %[vo], 0x1000, %[vo]\n\t"
      "global_load_dword %[v5], %[vo], %[vb]\n\t"
      "v_add_u32 %[vo], 0x1000, %[vo]\n\t"
      "global_load_dword %[v6], %[vo], %[vb]\n\t"
      "v_add_u32 %[vo], 0x1000, %[vo]\n\t"
      "global_load_dword %[v7], %[vo], %[vb]\n\t"
      "v_add_u32 %[vo], 0x1000, %[vo]\n\t"
      "global_load_dword %[v8], %[vo], %[vb]\n\t"
      "v_add_u32 %[vo], 0x1000, %[vo]\n\t"
      "global_load_dword %[v9], %[vo], %[vb]\n\t"
      "v_add_u32 %[vo], 0x1000, %[vo]\n\t"
      "global_load_dword %[v10], %[vo], %[vb]\n\t"
      "v_add_u32 %[vo], 0x1000, %[vo]\n\t"
      "global_load_dword %[v11], %[vo], %[vb]\n\t"
      "v_add_u32 %[vo], 0x1000, %[vo]\n\t"
      "global_load_dword %[v12], %[vo], %[vb]\n\t"
      "v_add_u32 %[vo], 0x1000, %[vo]\n\t"
      "global_load_dword %[v13], %[vo], %[vb]\n\t"
      "v_add_u32 %[vo], 0x1000, %[vo]\n\t"
      "global_load_dword %[v14], %[vo], %[vb]\n\t"
      "v_add_u32 %[vo], 0x1000, %[vo]\n\t"
      "global_load_dword %[v15], %[vo], %[vb]"
      : [k0]"=v"(ka[0]), [k1]"=v"(ka[1]), [k2]"=v"(ka[2]), [k3]"=v"(ka[3]),
        [v0]"=v"(va[0]), [v1]"=v"(va[1]), [v2]"=v"(va[2]), [v3]"=v"(va[3]),
        [v4]"=v"(va[4]), [v5]"=v"(va[5]), [v6]"=v"(va[6]), [v7]"=v"(va[7]),
        [v8]"=v"(va[8]), [v9]"=v"(va[9]), [v10]"=v"(va[10]), [v11]"=v"(va[11]),
        [v12]"=v"(va[12]), [v13]"=v"(va[13]), [v14]"=v"(va[14]), [v15]"=v"(va[15]),
        [vo]"+v"(voff)
      : [ko]"v"(koff), [kb]"s"(Kg), [vb]"s"(Vg)
      : "memory");
  };
  auto commit = [&](int buf) {
    // rule-18 fence: wait for async loads, then block scheduler motion across
    // (register-only cvtpk consumers would otherwise hoist above the wait)
    asm volatile("s_waitcnt vmcnt(0)" ::: "memory");
    __builtin_amdgcn_sched_barrier(0);
    SW k0, k1;
    k0.u[0] = cvtpk(ka[0].x, ka[0].y); k0.u[1] = cvtpk(ka[0].z, ka[0].w);
    k0.u[2] = cvtpk(ka[1].x, ka[1].y); k0.u[3] = cvtpk(ka[1].z, ka[1].w);
    k1.u[0] = cvtpk(ka[2].x, ka[2].y); k1.u[1] = cvtpk(ka[2].z, ka[2].w);
    k1.u[2] = cvtpk(ka[3].x, ka[3].y); k1.u[3] = cvtpk(ka[3].z, ka[3].w);
    short* kt = smem + buf * 8192;
    *reinterpret_cast<short8*>(&kt[(prow * 64 + kc0) ^ ((prow & 7) << 3)]) = k0.s8;
    *reinterpret_cast<short8*>(&kt[(prow * 64 + kc0 + 8) ^ ((prow & 7) << 3)]) = k1.s8;
    SW v0, v1;
    v0.u[0] = cvtpk(va[0], va[1]);   v0.u[1] = cvtpk(va[2], va[3]);
    v0.u[2] = cvtpk(va[4], va[5]);   v0.u[3] = cvtpk(va[6], va[7]);
    v1.u[0] = cvtpk(va[8], va[9]);   v1.u[1] = cvtpk(va[10], va[11]);
    v1.u[2] = cvtpk(va[12], va[13]); v1.u[3] = cvtpk(va[14], va[15]);
    short* vt = smem + 16384 + buf * 8192;
    const int ch0 = vs0 >> 3;
    *reinterpret_cast<short8*>(&vt[ve * 128 + (((ch0 + 0) ^ (ve & 7)) << 3)]) = v0.s8;
    *reinterpret_cast<short8*>(&vt[ve * 128 + (((ch0 + 1) ^ (ve & 7)) << 3)]) = v1.s8;
  };

  // one 64q x 128s round (this wave: 16 q x 64 s half), swapped operands
  auto round = [&](int Qb, int str, int curb) {
    const int sb = str * 128 + par * 64;
    const int qtop = Qb + qsub * 16;
    if (sb > qtop + 15) return;
    const short* ktb = smem + curb * 8192;
    const short* vtb = smem + 16384 + curb * 8192;

    // QK^T swapped: D[s][q], col = q = n; 4 cb blocks x k=64
    f32x4 sc[4] = {zero4, zero4, zero4, zero4};
    #pragma unroll
    for (int kc = 0; kc < 2; ++kc) {
      #pragma unroll
      for (int cb = 0; cb < 4; ++cb) {
        const int row = par * 64 + cb * 16 + n;
        const int idx = (row * 64 + kc * 32 + g * 8) ^ ((n & 7) << 3);
        short8 kf = *reinterpret_cast<const short8*>(&ktb[idx]);
        sc[cb] = MFMA16(kf, qf[kc], sc[cb]);
      }
    }

    const int qg = qtop + n;
    if (sb + 63 > qtop) {
      #pragma unroll
      for (int cb = 0; cb < 4; ++cb)
        #pragma unroll
        for (int r = 0; r < 4; ++r)
          if (sb + cb * 16 + sp4 + r > qg) sc[cb][r] = NEGBIG;
    }

    // row max: 15 lane-local fmax + VALU butterfly (permlane swaps)
    float m8 = fmaxf(fmaxf(fmaxf(sc[0][0], sc[0][1]), fmaxf(sc[0][2], sc[0][3])),
                     fmaxf(fmaxf(sc[1][0], sc[1][1]), fmaxf(sc[1][2], sc[1][3])));
    m8 = fmaxf(m8, fmaxf(fmaxf(fmaxf(sc[2][0], sc[2][1]), fmaxf(sc[2][2], sc[2][3])),
                         fmaxf(fmaxf(sc[3][0], sc[3][1]), fmaxf(sc[3][2], sc[3][3]))));
    m8 = bflymax(m8);

    // exact-identity rescale skip
    const bool resc = !__all(m8 <= mrun);
    if (resc) {
      const float mn = fmaxf(mrun, m8);
      const float afac = exp2v(mrun - mn);
      mrun = mn;
      lrun *= afac;
      #pragma unroll
      for (int e4 = 0; e4 < 4; ++e4)
        #pragma unroll
        for (int r = 0; r < 4; ++r) acc[e4][r] *= afac;
    }

    // P = exp2(S - m) -> packed bf16; per cb: word a (r0,r1), word b (r2,r3)
    unsigned ua[4], ub[4];
    #pragma unroll
    for (int cb = 0; cb < 4; ++cb) {
      ua[cb] = cvtpk(exp2v(sc[cb][0] - mrun), exp2v(sc[cb][1] - mrun));
      ub[cb] = cvtpk(exp2v(sc[cb][2] - mrun), exp2v(sc[cb][3] - mrun));
    }

    // P C-frag -> B-frag: pure-VALU permlane32 swaps
    plswap32(ua[0], ua[1]);
    plswap32(ub[0], ub[1]);
    plswap32(ua[2], ua[3]);
    plswap32(ub[2], ub[3]);
    SW pw0, pw1;
    pw0.u[0] = ua[0]; pw0.u[1] = ub[0]; pw0.u[2] = ua[1]; pw0.u[3] = ub[1];
    pw1.u[0] = ua[2]; pw1.u[1] = ub[2]; pw1.u[2] = ua[3]; pw1.u[3] = ub[3];

    // PV swapped: acc = V^T x P, two k=32 slices per e-chunk
    #pragma unroll
    for (int e4 = 0; e4 < 4; ++e4) {
      const int e = e4 * 16 + n;
      const int slot0 = (par * 8 + g) ^ (e & 7);
      const int slot1 = (par * 8 + 4 + g) ^ (e & 7);
      short8 vf0 = *reinterpret_cast<const short8*>(&vtb[e * 128 + (slot0 << 3)]);
      acc[e4] = MFMA16(vf0, pw0.s8, acc[e4]);
      short8 vf1 = *reinterpret_cast<const short8*>(&vtb[e * 128 + (slot1 << 3)]);
      acc[e4] = MFMA16(vf1, pw1.s8, acc[e4]);
    }

    // row sum of bf16-rounded P + VALU butterfly
    float rs = ((bflo(pw0.u[0]) + bfhi(pw0.u[0])) + (bflo(pw0.u[1]) + bfhi(pw0.u[1]))) +
               ((bflo(pw0.u[2]) + bfhi(pw0.u[2])) + (bflo(pw0.u[3]) + bfhi(pw0.u[3])));
    rs += ((bflo(pw1.u[0]) + bfhi(pw1.u[0])) + (bflo(pw1.u[1]) + bfhi(pw1.u[1]))) +
          ((bflo(pw1.u[2]) + bfhi(pw1.u[2])) + (bflo(pw1.u[3]) + bfhi(pw1.u[3])));
    lrun += bflysum(rs);
  };

  // merge parities via scratch overlaid on the retired buffer `curb`
  auto merge_store = [&](int Qb, int curb) {
    float* sA = reinterpret_cast<float*>(smem) + curb * 4096;         // rows 0..31
    float* sB = reinterpret_cast<float*>(smem) + 8192 + curb * 4096;  // rows 32..63 + m + l
    __syncthreads();
    const int row = qsub * 16 + n;
    if (par == 1) {
      float* base = (row < 32) ? (sA + row * 68) : (sB + (row - 32) * 68);
      #pragma unroll
      for (int e4 = 0; e4 < 4; ++e4)
        #pragma unroll
        for (int r = 0; r < 4; ++r) base[e4 * 16 + g * 4 + r] = acc[e4][r];
      if (g == 0) {
        sB[2176 + row] = mrun;
        sB[2240 + row] = lrun;
      }
    }
    __syncthreads();
    if (par == 0) {
      const float* base = (row < 32) ? (sA + row * 68) : (sB + (row - 32) * 68);
      const float m1 = sB[2176 + row];
      const float l1 = sB[2240 + row];
      const float mm = fmaxf(mrun, m1);
      const float a0 = exp2v(mrun - mm);
      const float a1 = exp2v(m1 - mm);
      const float inv = 1.0f / (lrun * a0 + l1 * a1);
      const int q = Qb + row;
      float* op = Og + ((size_t)(b * Lc + q) * Hc + h) * Ec;
      #pragma unroll
      for (int e4 = 0; e4 < 4; ++e4) {
        float4 v;
        v.x = (acc[e4][0] * a0 + base[e4 * 16 + g * 4 + 0] * a1) * inv;
        v.y = (acc[e4][1] * a0 + base[e4 * 16 + g * 4 + 1] * a1) * inv;
        v.z = (acc[e4][2] * a0 + base[e4 * 16 + g * 4 + 2] * a1) * inv;
        v.w = (acc[e4][3] * a0 + base[e4 * 16 + g * 4 + 3] * a1) * inv;
        *reinterpret_cast<float4*>(op + e4 * 16 + g * 4) = v;
      }
    }
  };

  // fused 17-round stream: rounds 0..RL-1 on tile lo, rest on tile hi
  constexpr int NRO = 17;
  loadq(QbL);
  issue(0);
  commit(0);
  __syncthreads();

  int cur = 0;
  for (int rd = 0; rd < NRO; ++rd) {
    const bool pre = (rd + 1 < NRO);
    if (pre) {
      const int nrd = rd + 1;
      const int nstr = (nrd < RL) ? nrd : nrd - RL;
      issue(nstr * 128);
    }
    const bool lo = (rd < RL);
    round(lo ? QbL : QbH, lo ? rd : rd - RL, cur);
    if (rd == RL - 1) {
      merge_store(QbL, cur);   // scratch overlays the just-consumed buffer
      #pragma unroll
      for (int e4 = 0; e4 < 4; ++e4) acc[e4] = zero4;
      mrun = NEGBIG;
      lrun = 0.f;
      loadq(QbH);
    }
    if (pre) commit(cur ^ 1);
    __syncthreads();
    cur ^= 1;
  }

  merge_store(QbH, cur ^ 1);   // last round consumed buffer cur^1 (post-flip)
}

extern "C" void kernel_launch(void* const* d_in, const int* in_sizes, int n_in,
                              void* d_out, int out_size, void* d_ws, size_t ws_size,
                              hipStream_t stream) {
  const float* Q = (const float*)d_in[0];
  const float* K = (const float*)d_in[1];
  const float* V = (const float*)d_in[2];
  float* O = (float*)d_out;
  dim3 grid(Bc * Hc * 16);   // 32 bh x 16 folded pairs, all identical work
  attn_fwd<<<grid, dim3(512), 0, stream>>>(Q, K, V, O);
}

// Round 15
// 66.159 us; speedup vs baseline: 1.3491x; 1.3491x over previous
//
#include <hip/hip_runtime.h>
#include <hip/hip_bf16.h>

typedef __attribute__((ext_vector_type(8))) short short8;
typedef __attribute__((ext_vector_type(4))) float f32x4;
typedef __attribute__((ext_vector_type(2))) unsigned uint2v;

#define MFMA16(a, b, c) __builtin_amdgcn_mfma_f32_16x16x32_bf16((a), (b), (c), 0, 0, 0)

constexpr int Bc = 2, Lc = 2048, Hc = 16, Ec = 64;
constexpr float LOG2E = 1.4426950408889634f;
constexpr float SCALE2 = 0.125f * LOG2E;   // fold log2(e): scores in log2 units
constexpr float NEGBIG = -3.0e38f;

union SW { short8 s8; unsigned u[4]; float4 f4; };

__device__ __forceinline__ unsigned cvtpk(float lo, float hi) {
  unsigned r;
  asm("v_cvt_pk_bf16_f32 %0, %1, %2" : "=v"(r) : "v"(lo), "v"(hi));
  return r;
}
__device__ __forceinline__ float exp2v(float x) {
  float r;
  asm("v_exp_f32 %0, %1" : "=v"(r) : "v"(x));
  return r;
}
__device__ __forceinline__ float bfhi(unsigned u) {
  return __builtin_bit_cast(float, u & 0xffff0000u);
}
__device__ __forceinline__ float bflo(unsigned u) {
  return __builtin_bit_cast(float, u << 16);
}
__device__ __forceinline__ void plswap32(unsigned& a, unsigned& b) {
  uint2v r = __builtin_amdgcn_permlane32_swap(a, b, false, false);
  a = r[0]; b = r[1];
}
__device__ __forceinline__ void plswap16(unsigned& a, unsigned& b) {
  uint2v r = __builtin_amdgcn_permlane16_swap(a, b, false, false);
  a = r[0]; b = r[1];
}
__device__ __forceinline__ float bflymax(float x) {
  unsigned a = __builtin_bit_cast(unsigned, x), b = a;
  plswap16(a, b);
  float y = fmaxf(__builtin_bit_cast(float, a), __builtin_bit_cast(float, b));
  a = __builtin_bit_cast(unsigned, y); b = a;
  plswap32(a, b);
  return fmaxf(__builtin_bit_cast(float, a), __builtin_bit_cast(float, b));
}
__device__ __forceinline__ float bflysum(float x) {
  unsigned a = __builtin_bit_cast(unsigned, x), b = a;
  plswap16(a, b);
  float y = __builtin_bit_cast(float, a) + __builtin_bit_cast(float, b);
  a = __builtin_bit_cast(unsigned, y); b = a;
  plswap32(a, b);
  return __builtin_bit_cast(float, a) + __builtin_bit_cast(float, b);
}

// One-time fp32 -> bf16 (RNE, same as in-loop cvtpk) pre-pass into d_ws.
__global__ __launch_bounds__(256)
void to_bf16(const float* __restrict__ src, uint4* __restrict__ dst) {
  const int i = blockIdx.x * 256 + threadIdx.x;   // grid sized exactly
  const float4* s = reinterpret_cast<const float4*>(src) + (size_t)i * 2;
  float4 a = s[0], b = s[1];
  uint4 o;
  o.x = cvtpk(a.x, a.y); o.y = cvtpk(a.z, a.w);
  o.z = cvtpk(b.x, b.y); o.w = cvtpk(b.z, b.w);
  dst[i] = o;
}

__global__ __launch_bounds__(512, 2)
void attn_fwd(const float* __restrict__ Qg, const unsigned short* __restrict__ Kb,
              const unsigned short* __restrict__ Vb, float* __restrict__ Og) {
  // smem (shorts), NT=128 s-tile double-buffered:
  //  kt[b]: [128][64] bf16 at b*8192, K row s at prow=pi(s), idx ^ ((prow&7)<<3)
  //  vt[b]: [64 e][128 s] bf16 at 16384 + b*8192, chunk slot = (s>>3) ^ (e&7)
  // merge scratch overlays the RETIRED buffer.
  __shared__ __align__(16) short smem[32768];

  // causal fold: block owns q-tile pair (i, 31-i): exactly 17 uniform rounds
  const int bid = blockIdx.x;
  const int pair = bid & 15;
  const int bh = bid >> 4;
  const int h = bh & (Hc - 1);
  const int b = bh >> 4;
  const int iLo = pair;
  const int QbL = iLo * 64;
  const int QbH = (31 - pair) * 64;
  const int RL = (iLo + 2) >> 1;              // lo-tile rounds; RL + RH = 17

  const int t = threadIdx.x;
  const int w = t >> 6;        // 0..7
  const int qsub = w & 3;      // q sub-block (16 rows)
  const int par = w >> 2;      // 64-s half of the 128-row tile
  const int l = t & 63;
  const int n = l & 15;
  const int g = l >> 4;
  const int sp4 = ((g & 1) << 3) | ((g >> 1) << 2);  // pi(g)*4

  const f32x4 zero4 = {0.f, 0.f, 0.f, 0.f};

  // Q fragments (B-operand: col=q=lane&15, k=e=(lane>>4)*8+j)
  short8 qf[2];
  auto loadq = [&](int Qb) {
    const int q = Qb + qsub * 16 + n;
    const float* qp = Qg + ((size_t)(b * Lc + q) * Hc + h) * Ec + g * 8;
    SW a0, a1, b0, b1, r0, r1;
    a0.f4 = reinterpret_cast<const float4*>(qp)[0];
    a1.f4 = reinterpret_cast<const float4*>(qp)[1];
    b0.f4 = reinterpret_cast<const float4*>(qp + 32)[0];
    b1.f4 = reinterpret_cast<const float4*>(qp + 32)[1];
    r0.u[0] = cvtpk(a0.f4.x * SCALE2, a0.f4.y * SCALE2);
    r0.u[1] = cvtpk(a0.f4.z * SCALE2, a0.f4.w * SCALE2);
    r0.u[2] = cvtpk(a1.f4.x * SCALE2, a1.f4.y * SCALE2);
    r0.u[3] = cvtpk(a1.f4.z * SCALE2, a1.f4.w * SCALE2);
    r1.u[0] = cvtpk(b0.f4.x * SCALE2, b0.f4.y * SCALE2);
    r1.u[1] = cvtpk(b0.f4.z * SCALE2, b0.f4.w * SCALE2);
    r1.u[2] = cvtpk(b1.f4.x * SCALE2, b1.f4.y * SCALE2);
    r1.u[3] = cvtpk(b1.f4.z * SCALE2, b1.f4.w * SCALE2);
    qf[0] = r0.s8;
    qf[1] = r1.s8;
  };

  // acc[e4][r] = O^T[e = e4*16 + g*4 + r][q = n]; per-lane scalar m,l
  f32x4 acc[4] = {zero4, zero4, zero4, zero4};
  float mrun = NEGBIG, lrun = 0.f;

  // staging: 512 threads stage 128 rows of K (pi-permuted) and V^T per round
  const int srow = t >> 2;                               // 0..127
  const int prow = (srow & ~12) | ((srow & 4) << 1) | ((srow & 8) >> 1);
  const int kc0 = (t & 3) * 16;                          // 16-col bf16 chunk
  const int ve = l, vs0 = w * 16;                        // V^T: e=lane, 16 s rows

  float4 kA, kB;          // 2 x dwordx4 = 16 bf16
  unsigned va16[16];      // 16 x ushort (zero-extended)

  // Forced-async bf16 stage: volatile asm loads issue HERE (unsinkable).
  auto issue = [&](int r0) {
    unsigned koff = (unsigned)((((b * Lc + r0 + srow) * Hc + h) * Ec + kc0) * 2);
    unsigned voff = (unsigned)((((b * Lc + r0 + vs0) * Hc + h) * Ec + ve) * 2);
    asm volatile(
      "global_load_dwordx4 %[k0], %[ko], %[kb]\n\t"
      "global_load_dwordx4 %[k1], %[ko], %[kb] offset:16\n\t"
      "global_load_ushort %[v0], %[vo], %[vb]\n\t"
      "v_add_u32 %[vo], 0x800, %[vo]\n\t"
      "global_load_ushort %[v1], %[vo], %[vb]\n\t"
      "v_add_u32 %[vo], 0x800, %[vo]\n\t"
      "global_load_ushort %[v2], %[vo], %[vb]\n\t"
      "v_add_u32 %[vo], 0x800, %[vo]\n\t"
      "global_load_ushort %[v3], %[vo], %[vb]\n\t"
      "v_add_u32 %[vo], 0x800, %[vo]\n\t"
      "global_load_ushort %[v4], %[vo], %[vb]\n\t"
      "v_add_u32 %[vo], 0x800, %[vo]\n\t"
      "global_load_ushort %[v5], %[vo], %[vb]\n\t"
      "v_add_u32 %[vo], 0x800, %[vo]\n\t"
      "global_load_ushort %[v6], %[vo], %[vb]\n\t"
      "v_add_u32 %[vo], 0x800, %[vo]\n\t"
      "global_load_ushort %[v7], %[vo], %[vb]\n\t"
      "v_add_u32 %[vo], 0x800, %[vo]\n\t"
      "global_load_ushort %[v8], %[vo], %[vb]\n\t"
      "v_add_u32 %[vo], 0x800, %[vo]\n\t"
      "global_load_ushort %[v9], %[vo], %[vb]\n\t"
      "v_add_u32 %[vo], 0x800, %[vo]\n\t"
      "global_load_ushort %[v10], %[vo], %[vb]\n\t"
      "v_add_u32 %[vo], 0x800, %[vo]\n\t"
      "global_load_ushort %[v11], %[vo], %[vb]\n\t"
      "v_add_u32 %[vo], 0x800, %[vo]\n\t"
      "global_load_ushort %[v12], %[vo], %[vb]\n\t"
      "v_add_u32 %[vo], 0x800, %[vo]\n\t"
      "global_load_ushort %[v13], %[vo], %[vb]\n\t"
      "v_add_u32 %[vo], 0x800, %[vo]\n\t"
      "global_load_ushort %[v14], %[vo], %[vb]\n\t"
      "v_add_u32 %[vo], 0x800, %[vo]\n\t"
      "global_load_ushort %[v15], %[vo], %[vb]"
      : [k0]"=v"(kA), [k1]"=v"(kB),
        [v0]"=v"(va16[0]), [v1]"=v"(va16[1]), [v2]"=v"(va16[2]), [v3]"=v"(va16[3]),
        [v4]"=v"(va16[4]), [v5]"=v"(va16[5]), [v6]"=v"(va16[6]), [v7]"=v"(va16[7]),
        [v8]"=v"(va16[8]), [v9]"=v"(va16[9]), [v10]"=v"(va16[10]), [v11]"=v"(va16[11]),
        [v12]"=v"(va16[12]), [v13]"=v"(va16[13]), [v14]"=v"(va16[14]), [v15]"=v"(va16[15]),
        [vo]"+v"(voff)
      : [ko]"v"(koff), [kb]"s"(Kb), [vb]"s"(Vb)
      : "memory");
  };
  auto commit = [&](int buf) {
    // K first: only the 2 K loads must be done (16 V still outstanding)
    asm volatile("s_waitcnt vmcnt(16)" ::: "memory");
    __builtin_amdgcn_sched_barrier(0);
    short* kt = smem + buf * 8192;
    *reinterpret_cast<short8*>(&kt[(prow * 64 + kc0) ^ ((prow & 7) << 3)]) =
        *reinterpret_cast<short8*>(&kA);
    *reinterpret_cast<short8*>(&kt[(prow * 64 + kc0 + 8) ^ ((prow & 7) << 3)]) =
        *reinterpret_cast<short8*>(&kB);
    asm volatile("s_waitcnt vmcnt(0)" ::: "memory");
    __builtin_amdgcn_sched_barrier(0);
    SW v0, v1;
    v0.u[0] = va16[0] | (va16[1] << 16);
    v0.u[1] = va16[2] | (va16[3] << 16);
    v0.u[2] = va16[4] | (va16[5] << 16);
    v0.u[3] = va16[6] | (va16[7] << 16);
    v1.u[0] = va16[8] | (va16[9] << 16);
    v1.u[1] = va16[10] | (va16[11] << 16);
    v1.u[2] = va16[12] | (va16[13] << 16);
    v1.u[3] = va16[14] | (va16[15] << 16);
    short* vt = smem + 16384 + buf * 8192;
    const int ch0 = vs0 >> 3;
    *reinterpret_cast<short8*>(&vt[ve * 128 + (((ch0 + 0) ^ (ve & 7)) << 3)]) = v0.s8;
    *reinterpret_cast<short8*>(&vt[ve * 128 + (((ch0 + 1) ^ (ve & 7)) << 3)]) = v1.s8;
  };

  // one 64q x 128s round (this wave: 16 q x 64 s half), swapped operands
  auto round = [&](int Qb, int str, int curb) {
    const int sb = str * 128 + par * 64;
    const int qtop = Qb + qsub * 16;
    if (sb > qtop + 15) return;
    const short* ktb = smem + curb * 8192;
    const short* vtb = smem + 16384 + curb * 8192;

    // QK^T swapped: D[s][q], col = q = n; 4 cb blocks x k=64
    f32x4 sc[4] = {zero4, zero4, zero4, zero4};
    #pragma unroll
    for (int kc = 0; kc < 2; ++kc) {
      #pragma unroll
      for (int cb = 0; cb < 4; ++cb) {
        const int row = par * 64 + cb * 16 + n;
        const int idx = (row * 64 + kc * 32 + g * 8) ^ ((n & 7) << 3);
        short8 kf = *reinterpret_cast<const short8*>(&ktb[idx]);
        sc[cb] = MFMA16(kf, qf[kc], sc[cb]);
      }
    }

    const int qg = qtop + n;
    if (sb + 63 > qtop) {
      #pragma unroll
      for (int cb = 0; cb < 4; ++cb)
        #pragma unroll
        for (int r = 0; r < 4; ++r)
          if (sb + cb * 16 + sp4 + r > qg) sc[cb][r] = NEGBIG;
    }

    // row max: 15 lane-local fmax + VALU butterfly
    float m8 = fmaxf(fmaxf(fmaxf(sc[0][0], sc[0][1]), fmaxf(sc[0][2], sc[0][3])),
                     fmaxf(fmaxf(sc[1][0], sc[1][1]), fmaxf(sc[1][2], sc[1][3])));
    m8 = fmaxf(m8, fmaxf(fmaxf(fmaxf(sc[2][0], sc[2][1]), fmaxf(sc[2][2], sc[2][3])),
                         fmaxf(fmaxf(sc[3][0], sc[3][1]), fmaxf(sc[3][2], sc[3][3]))));
    m8 = bflymax(m8);

    // exact-identity rescale skip
    const bool resc = !__all(m8 <= mrun);
    if (resc) {
      const float mn = fmaxf(mrun, m8);
      const float afac = exp2v(mrun - mn);
      mrun = mn;
      lrun *= afac;
      #pragma unroll
      for (int e4 = 0; e4 < 4; ++e4)
        #pragma unroll
        for (int r = 0; r < 4; ++r) acc[e4][r] *= afac;
    }

    // P = exp2(S - m) -> packed bf16
    unsigned ua[4], ub[4];
    #pragma unroll
    for (int cb = 0; cb < 4; ++cb) {
      ua[cb] = cvtpk(exp2v(sc[cb][0] - mrun), exp2v(sc[cb][1] - mrun));
      ub[cb] = cvtpk(exp2v(sc[cb][2] - mrun), exp2v(sc[cb][3] - mrun));
    }

    // P C-frag -> B-frag: pure-VALU permlane32 swaps
    plswap32(ua[0], ua[1]);
    plswap32(ub[0], ub[1]);
    plswap32(ua[2], ua[3]);
    plswap32(ub[2], ub[3]);
    SW pw0, pw1;
    pw0.u[0] = ua[0]; pw0.u[1] = ub[0]; pw0.u[2] = ua[1]; pw0.u[3] = ub[1];
    pw1.u[0] = ua[2]; pw1.u[1] = ub[2]; pw1.u[2] = ua[3]; pw1.u[3] = ub[3];

    // PV swapped: acc = V^T x P, two k=32 slices per e-chunk
    #pragma unroll
    for (int e4 = 0; e4 < 4; ++e4) {
      const int e = e4 * 16 + n;
      const int slot0 = (par * 8 + g) ^ (e & 7);
      const int slot1 = (par * 8 + 4 + g) ^ (e & 7);
      short8 vf0 = *reinterpret_cast<const short8*>(&vtb[e * 128 + (slot0 << 3)]);
      acc[e4] = MFMA16(vf0, pw0.s8, acc[e4]);
      short8 vf1 = *reinterpret_cast<const short8*>(&vtb[e * 128 + (slot1 << 3)]);
      acc[e4] = MFMA16(vf1, pw1.s8, acc[e4]);
    }

    // row sum of bf16-rounded P + VALU butterfly
    float rs = ((bflo(pw0.u[0]) + bfhi(pw0.u[0])) + (bflo(pw0.u[1]) + bfhi(pw0.u[1]))) +
               ((bflo(pw0.u[2]) + bfhi(pw0.u[2])) + (bflo(pw0.u[3]) + bfhi(pw0.u[3])));
    rs += ((bflo(pw1.u[0]) + bfhi(pw1.u[0])) + (bflo(pw1.u[1]) + bfhi(pw1.u[1]))) +
          ((bflo(pw1.u[2]) + bfhi(pw1.u[2])) + (bflo(pw1.u[3]) + bfhi(pw1.u[3])));
    lrun += bflysum(rs);
  };

  // merge parities via scratch overlaid on the retired buffer `curb`
  auto merge_store = [&](int Qb, int curb) {
    float* sA = reinterpret_cast<float*>(smem) + curb * 4096;         // rows 0..31
    float* sB = reinterpret_cast<float*>(smem) + 8192 + curb * 4096;  // rows 32..63 + m + l
    __syncthreads();
    const int row = qsub * 16 + n;
    if (par == 1) {
      float* base = (row < 32) ? (sA + row * 68) : (sB + (row - 32) * 68);
      #pragma unroll
      for (int e4 = 0; e4 < 4; ++e4)
        #pragma unroll
        for (int r = 0; r < 4; ++r) base[e4 * 16 + g * 4 + r] = acc[e4][r];
      if (g == 0) {
        sB[2176 + row] = mrun;
        sB[2240 + row] = lrun;
      }
    }
    __syncthreads();
    if (par == 0) {
      const float* base = (row < 32) ? (sA + row * 68) : (sB + (row - 32) * 68);
      const float m1 = sB[2176 + row];
      const float l1 = sB[2240 + row];
      const float mm = fmaxf(mrun, m1);
      const float a0 = exp2v(mrun - mm);
      const float a1 = exp2v(m1 - mm);
      const float inv = 1.0f / (lrun * a0 + l1 * a1);
      const int q = Qb + row;
      float* op = Og + ((size_t)(b * Lc + q) * Hc + h) * Ec;
      #pragma unroll
      for (int e4 = 0; e4 < 4; ++e4) {
        float4 v;
        v.x = (acc[e4][0] * a0 + base[e4 * 16 + g * 4 + 0] * a1) * inv;
        v.y = (acc[e4][1] * a0 + base[e4 * 16 + g * 4 + 1] * a1) * inv;
        v.z = (acc[e4][2] * a0 + base[e4 * 16 + g * 4 + 2] * a1) * inv;
        v.w = (acc[e4][3] * a0 + base[e4 * 16 + g * 4 + 3] * a1) * inv;
        *reinterpret_cast<float4*>(op + e4 * 16 + g * 4) = v;
      }
    }
  };

  // fused 17-round stream: rounds 0..RL-1 on tile lo, rest on tile hi
  constexpr int NRO = 17;
  loadq(QbL);
  issue(0);
  commit(0);
  __syncthreads();

  int cur = 0;
  for (int rd = 0; rd < NRO; ++rd) {
    const bool pre = (rd + 1 < NRO);
    if (pre) {
      const int nrd = rd + 1;
      const int nstr = (nrd < RL) ? nrd : nrd - RL;
      issue(nstr * 128);
    }
    const bool lo = (rd < RL);
    round(lo ? QbL : QbH, lo ? rd : rd - RL, cur);
    if (rd == RL - 1) {
      merge_store(QbL, cur);   // scratch overlays the just-consumed buffer
      #pragma unroll
      for (int e4 = 0; e4 < 4; ++e4) acc[e4] = zero4;
      mrun = NEGBIG;
      lrun = 0.f;
      loadq(QbH);
    }
    if (pre) commit(cur ^ 1);
    __syncthreads();
    cur ^= 1;
  }

  merge_store(QbH, cur ^ 1);
}

extern "C" void kernel_launch(void* const* d_in, const int* in_sizes, int n_in,
                              void* d_out, int out_size, void* d_ws, size_t ws_size,
                              hipStream_t stream) {
  const float* Q = (const float*)d_in[0];
  const float* K = (const float*)d_in[1];
  const float* V = (const float*)d_in[2];
  float* O = (float*)d_out;
  // bf16 scratch: K at 0, V at 8 MiB (needs 16 MiB of ws)
  unsigned short* Kb = (unsigned short*)d_ws;
  unsigned short* Vb = (unsigned short*)((char*)d_ws + (size_t)Bc * Lc * Hc * Ec * 2);
  const int n8 = Bc * Lc * Hc * Ec / 8;   // 524288 8-elem chunks
  to_bf16<<<dim3(n8 / 256), dim3(256), 0, stream>>>(K, (uint4*)Kb);
  to_bf16<<<dim3(n8 / 256), dim3(256), 0, stream>>>(V, (uint4*)Vb);
  dim3 grid(Bc * Hc * 16);   // 32 bh x 16 folded pairs, all identical work
  attn_fwd<<<grid, dim3(512), 0, stream>>>(Q, Kb, Vb, O);
}

// Round 16
// 63.564 us; speedup vs baseline: 1.4042x; 1.0408x over previous
//
#include <hip/hip_runtime.h>
#include <hip/hip_bf16.h>

typedef __attribute__((ext_vector_type(8))) short short8;
typedef __attribute__((ext_vector_type(4))) float f32x4;
typedef __attribute__((ext_vector_type(2))) unsigned uint2v;

#define MFMA16(a, b, c) __builtin_amdgcn_mfma_f32_16x16x32_bf16((a), (b), (c), 0, 0, 0)

constexpr int Bc = 2, Lc = 2048, Hc = 16, Ec = 64;
constexpr float LOG2E = 1.4426950408889634f;
constexpr float SCALE2 = 0.125f * LOG2E;   // fold log2(e): scores in log2 units
constexpr float NEGBIG = -3.0e38f;

union SW { short8 s8; unsigned u[4]; float4 f4; };

__device__ __forceinline__ unsigned cvtpk(float lo, float hi) {
  unsigned r;
  asm("v_cvt_pk_bf16_f32 %0, %1, %2" : "=v"(r) : "v"(lo), "v"(hi));
  return r;
}
__device__ __forceinline__ float exp2v(float x) {
  float r;
  asm("v_exp_f32 %0, %1" : "=v"(r) : "v"(x));
  return r;
}
__device__ __forceinline__ void plswap32(unsigned& a, unsigned& b) {
  uint2v r = __builtin_amdgcn_permlane32_swap(a, b, false, false);
  a = r[0]; b = r[1];
}
__device__ __forceinline__ void plswap16(unsigned& a, unsigned& b) {
  uint2v r = __builtin_amdgcn_permlane16_swap(a, b, false, false);
  a = r[0]; b = r[1];
}
__device__ __forceinline__ float bflymax(float x) {
  unsigned a = __builtin_bit_cast(unsigned, x), b = a;
  plswap16(a, b);
  float y = fmaxf(__builtin_bit_cast(float, a), __builtin_bit_cast(float, b));
  a = __builtin_bit_cast(unsigned, y); b = a;
  plswap32(a, b);
  return fmaxf(__builtin_bit_cast(float, a), __builtin_bit_cast(float, b));
}

// Fused prepass: blocks [0,2048) convert K fp32->bf16 (RNE, same as cvtpk);
// blocks [2048,3072) transpose V into Vt[bh][e][s] bf16.
__global__ __launch_bounds__(256)
void prep(const float* __restrict__ K, const float* __restrict__ V,
          uint4* __restrict__ Kb, unsigned short* __restrict__ Vt) {
  const int bid = blockIdx.x;
  const int t = threadIdx.x;
  if (bid < 2048) {
    const int i = bid * 256 + t;
    const float4* s = reinterpret_cast<const float4*>(K) + (size_t)i * 2;
    float4 a = s[0], b = s[1];
    uint4 o;
    o.x = cvtpk(a.x, a.y); o.y = cvtpk(a.z, a.w);
    o.z = cvtpk(b.x, b.y); o.w = cvtpk(b.z, b.w);
    Kb[i] = o;
  } else {
    const int vw = (bid - 2048) * 4 + (t >> 6);   // 0..4095
    const int l = t & 63;
    const int bh = vw >> 7;                       // 0..31
    const int s0 = (vw & 127) * 16;
    const float* vp = V + ((size_t)(bh >> 4) * Lc + s0) * (Hc * Ec) +
                      (bh & 15) * Ec + l;
    float va[16];
    #pragma unroll
    for (int j = 0; j < 16; ++j) va[j] = vp[j * (Hc * Ec)];
    uint4 o0, o1;
    o0.x = cvtpk(va[0], va[1]);   o0.y = cvtpk(va[2], va[3]);
    o0.z = cvtpk(va[4], va[5]);   o0.w = cvtpk(va[6], va[7]);
    o1.x = cvtpk(va[8], va[9]);   o1.y = cvtpk(va[10], va[11]);
    o1.z = cvtpk(va[12], va[13]); o1.w = cvtpk(va[14], va[15]);
    uint4* dst = reinterpret_cast<uint4*>(Vt + ((size_t)bh * Ec + l) * Lc + s0);
    dst[0] = o0;
    dst[1] = o1;
  }
}

__global__ __launch_bounds__(512, 2)
void attn_fwd(const float* __restrict__ Qg, const unsigned short* __restrict__ Kb,
              const unsigned short* __restrict__ Vt, float* __restrict__ Og) {
  // smem (shorts), NT=128 s-tile double-buffered:
  //  kt[b]: [128][64] bf16 at b*8192, K row s at prow=pi(s), idx ^ ((prow&7)<<3)
  //  vt[b]: [64 e][128 s] bf16 at 16384 + b*8192, chunk slot = (s>>3) ^ (e&7)
  // merge scratch overlays the RETIRED buffer.
  __shared__ __align__(16) short smem[32768];

  // causal fold: block owns q-tile pair (i, 31-i): exactly 17 uniform rounds
  const int bid = blockIdx.x;
  const int pair = bid & 15;
  const int bh = bid >> 4;
  const int h = bh & (Hc - 1);
  const int b = bh >> 4;
  const int iLo = pair;
  const int QbL = iLo * 64;
  const int QbH = (31 - pair) * 64;
  const int RL = (iLo + 2) >> 1;              // lo-tile rounds; RL + RH = 17

  const int t = threadIdx.x;
  const int w = t >> 6;        // 0..7
  const int qsub = w & 3;      // q sub-block (16 rows)
  const int par = w >> 2;      // 64-s half of the 128-row tile
  const int l = t & 63;
  const int n = l & 15;
  const int g = l >> 4;
  const int sp4 = ((g & 1) << 3) | ((g >> 1) << 2);  // pi(g)*4

  const f32x4 zero4 = {0.f, 0.f, 0.f, 0.f};
  short8 onesv;
  #pragma unroll
  for (int j = 0; j < 8; ++j) onesv[j] = (short)0x3F80;  // bf16 1.0

  // Q fragments (B-operand: col=q=lane&15, k=e=(lane>>4)*8+j)
  short8 qf[2];
  auto loadq = [&](int Qb) {
    const int q = Qb + qsub * 16 + n;
    const float* qp = Qg + ((size_t)(b * Lc + q) * Hc + h) * Ec + g * 8;
    SW a0, a1, b0, b1, r0, r1;
    a0.f4 = reinterpret_cast<const float4*>(qp)[0];
    a1.f4 = reinterpret_cast<const float4*>(qp)[1];
    b0.f4 = reinterpret_cast<const float4*>(qp + 32)[0];
    b1.f4 = reinterpret_cast<const float4*>(qp + 32)[1];
    r0.u[0] = cvtpk(a0.f4.x * SCALE2, a0.f4.y * SCALE2);
    r0.u[1] = cvtpk(a0.f4.z * SCALE2, a0.f4.w * SCALE2);
    r0.u[2] = cvtpk(a1.f4.x * SCALE2, a1.f4.y * SCALE2);
    r0.u[3] = cvtpk(a1.f4.z * SCALE2, a1.f4.w * SCALE2);
    r1.u[0] = cvtpk(b0.f4.x * SCALE2, b0.f4.y * SCALE2);
    r1.u[1] = cvtpk(b0.f4.z * SCALE2, b0.f4.w * SCALE2);
    r1.u[2] = cvtpk(b1.f4.x * SCALE2, b1.f4.y * SCALE2);
    r1.u[3] = cvtpk(b1.f4.z * SCALE2, b1.f4.w * SCALE2);
    qf[0] = r0.s8;
    qf[1] = r1.s8;
  };

  // acc[e4][r] = O^T[e = e4*16 + g*4 + r][q = n]; per-lane scalar m,l
  f32x4 acc[4] = {zero4, zero4, zero4, zero4};
  float mrun = NEGBIG, lrun = 0.f;

  // staging: 512 threads stage 128 rows of K (pi-permuted) and V^T per round
  const int srow = t >> 2;                               // 0..127
  const int prow = (srow & ~12) | ((srow & 4) << 1) | ((srow & 8) >> 1);
  const int kc0 = (t & 3) * 16;                          // 16-col bf16 chunk
  const int ve = l, vs0 = w * 16;                        // V^T: e=lane, 16 s rows

  float4 kA, kB, vA, vB;   // 4 x dwordx4 bf16

  // Forced-async bf16 stage: volatile asm loads issue HERE (unsinkable).
  auto issue = [&](int r0) {
    unsigned koff = (unsigned)((((b * Lc + r0 + srow) * Hc + h) * Ec + kc0) * 2);
    unsigned voff = (unsigned)((((bh * Ec + ve) * Lc) + r0 + vs0) * 2);
    asm volatile(
      "global_load_dwordx4 %[k0], %[ko], %[kb]\n\t"
      "global_load_dwordx4 %[k1], %[ko], %[kb] offset:16\n\t"
      "global_load_dwordx4 %[v0], %[vo], %[vb]\n\t"
      "global_load_dwordx4 %[v1], %[vo], %[vb] offset:16"
      : [k0]"=v"(kA), [k1]"=v"(kB), [v0]"=v"(vA), [v1]"=v"(vB)
      : [ko]"v"(koff), [vo]"v"(voff), [kb]"s"(Kb), [vb]"s"(Vt)
      : "memory");
  };
  auto commit = [&](int buf) {
    // K first (2 V loads may remain outstanding)
    asm volatile("s_waitcnt vmcnt(2)" ::: "memory");
    __builtin_amdgcn_sched_barrier(0);
    short* kt = smem + buf * 8192;
    *reinterpret_cast<short8*>(&kt[(prow * 64 + kc0) ^ ((prow & 7) << 3)]) =
        *reinterpret_cast<short8*>(&kA);
    *reinterpret_cast<short8*>(&kt[(prow * 64 + kc0 + 8) ^ ((prow & 7) << 3)]) =
        *reinterpret_cast<short8*>(&kB);
    asm volatile("s_waitcnt vmcnt(0)" ::: "memory");
    __builtin_amdgcn_sched_barrier(0);
    short* vt = smem + 16384 + buf * 8192;
    const int ch0 = vs0 >> 3;
    *reinterpret_cast<short8*>(&vt[ve * 128 + (((ch0 + 0) ^ (ve & 7)) << 3)]) =
        *reinterpret_cast<short8*>(&vA);
    *reinterpret_cast<short8*>(&vt[ve * 128 + (((ch0 + 1) ^ (ve & 7)) << 3)]) =
        *reinterpret_cast<short8*>(&vB);
  };

  // one 64q x 128s round (this wave: 16 q x 64 s half), swapped operands
  auto round = [&](int Qb, int str, int curb) {
    const int sb = str * 128 + par * 64;
    const int qtop = Qb + qsub * 16;
    if (sb > qtop + 15) return;
    const short* ktb = smem + curb * 8192;
    const short* vtb = smem + 16384 + curb * 8192;

    // QK^T swapped: D[s][q], col = q = n; 4 cb blocks x k=64
    f32x4 sc[4] = {zero4, zero4, zero4, zero4};
    #pragma unroll
    for (int kc = 0; kc < 2; ++kc) {
      #pragma unroll
      for (int cb = 0; cb < 4; ++cb) {
        const int row = par * 64 + cb * 16 + n;
        const int idx = (row * 64 + kc * 32 + g * 8) ^ ((n & 7) << 3);
        short8 kf = *reinterpret_cast<const short8*>(&ktb[idx]);
        sc[cb] = MFMA16(kf, qf[kc], sc[cb]);
      }
    }

    const int qg = qtop + n;
    if (sb + 63 > qtop) {
      #pragma unroll
      for (int cb = 0; cb < 4; ++cb)
        #pragma unroll
        for (int r = 0; r < 4; ++r)
          if (sb + cb * 16 + sp4 + r > qg) sc[cb][r] = NEGBIG;
    }

    // row max: 15 lane-local fmax + VALU butterfly
    float m8 = fmaxf(fmaxf(fmaxf(sc[0][0], sc[0][1]), fmaxf(sc[0][2], sc[0][3])),
                     fmaxf(fmaxf(sc[1][0], sc[1][1]), fmaxf(sc[1][2], sc[1][3])));
    m8 = fmaxf(m8, fmaxf(fmaxf(fmaxf(sc[2][0], sc[2][1]), fmaxf(sc[2][2], sc[2][3])),
                         fmaxf(fmaxf(sc[3][0], sc[3][1]), fmaxf(sc[3][2], sc[3][3]))));
    m8 = bflymax(m8);

    // exact-identity rescale skip
    const bool resc = !__all(m8 <= mrun);
    if (resc) {
      const float mn = fmaxf(mrun, m8);
      const float afac = exp2v(mrun - mn);
      mrun = mn;
      lrun *= afac;
      #pragma unroll
      for (int e4 = 0; e4 < 4; ++e4)
        #pragma unroll
        for (int r = 0; r < 4; ++r) acc[e4][r] *= afac;
    }

    // P = exp2(S - m) -> packed bf16
    unsigned ua[4], ub[4];
    #pragma unroll
    for (int cb = 0; cb < 4; ++cb) {
      ua[cb] = cvtpk(exp2v(sc[cb][0] - mrun), exp2v(sc[cb][1] - mrun));
      ub[cb] = cvtpk(exp2v(sc[cb][2] - mrun), exp2v(sc[cb][3] - mrun));
    }

    // P C-frag -> B-frag: pure-VALU permlane32 swaps
    plswap32(ua[0], ua[1]);
    plswap32(ub[0], ub[1]);
    plswap32(ua[2], ua[3]);
    plswap32(ub[2], ub[3]);
    SW pw0, pw1;
    pw0.u[0] = ua[0]; pw0.u[1] = ub[0]; pw0.u[2] = ua[1]; pw0.u[3] = ub[1];
    pw1.u[0] = ua[2]; pw1.u[1] = ub[2]; pw1.u[2] = ua[3]; pw1.u[3] = ub[3];

    // PV swapped: acc = V^T x P, two k=32 slices per e-chunk
    #pragma unroll
    for (int e4 = 0; e4 < 4; ++e4) {
      const int e = e4 * 16 + n;
      const int slot0 = (par * 8 + g) ^ (e & 7);
      const int slot1 = (par * 8 + 4 + g) ^ (e & 7);
      short8 vf0 = *reinterpret_cast<const short8*>(&vtb[e * 128 + (slot0 << 3)]);
      acc[e4] = MFMA16(vf0, pw0.s8, acc[e4]);
      short8 vf1 = *reinterpret_cast<const short8*>(&vtb[e * 128 + (slot1 << 3)]);
      acc[e4] = MFMA16(vf1, pw1.s8, acc[e4]);
    }

    // row sum via ones-MFMA: D[i][q] = sum_s P[s][q], lane col q = n
    f32x4 rs = MFMA16(onesv, pw0.s8, zero4);
    rs = MFMA16(onesv, pw1.s8, rs);
    lrun += rs[0];
  };

  // merge parities via scratch overlaid on the retired buffer `curb`
  auto merge_store = [&](int Qb, int curb) {
    float* sA = reinterpret_cast<float*>(smem) + curb * 4096;         // rows 0..31
    float* sB = reinterpret_cast<float*>(smem) + 8192 + curb * 4096;  // rows 32..63 + m + l
    __syncthreads();
    const int row = qsub * 16 + n;
    if (par == 1) {
      float* base = (row < 32) ? (sA + row * 68) : (sB + (row - 32) * 68);
      #pragma unroll
      for (int e4 = 0; e4 < 4; ++e4)
        #pragma unroll
        for (int r = 0; r < 4; ++r) base[e4 * 16 + g * 4 + r] = acc[e4][r];
      if (g == 0) {
        sB[2176 + row] = mrun;
        sB[2240 + row] = lrun;
      }
    }
    __syncthreads();
    if (par == 0) {
      const float* base = (row < 32) ? (sA + row * 68) : (sB + (row - 32) * 68);
      const float m1 = sB[2176 + row];
      const float l1 = sB[2240 + row];
      const float mm = fmaxf(mrun, m1);
      const float a0 = exp2v(mrun - mm);
      const float a1 = exp2v(m1 - mm);
      const float inv = 1.0f / (lrun * a0 + l1 * a1);
      const int q = Qb + row;
      float* op = Og + ((size_t)(b * Lc + q) * Hc + h) * Ec;
      #pragma unroll
      for (int e4 = 0; e4 < 4; ++e4) {
        float4 v;
        v.x = (acc[e4][0] * a0 + base[e4 * 16 + g * 4 + 0] * a1) * inv;
        v.y = (acc[e4][1] * a0 + base[e4 * 16 + g * 4 + 1] * a1) * inv;
        v.z = (acc[e4][2] * a0 + base[e4 * 16 + g * 4 + 2] * a1) * inv;
        v.w = (acc[e4][3] * a0 + base[e4 * 16 + g * 4 + 3] * a1) * inv;
        *reinterpret_cast<float4*>(op + e4 * 16 + g * 4) = v;
      }
    }
  };

  // fused 17-round stream: rounds 0..RL-1 on tile lo, rest on tile hi
  constexpr int NRO = 17;
  loadq(QbL);
  issue(0);
  commit(0);
  __syncthreads();

  int cur = 0;
  for (int rd = 0; rd < NRO; ++rd) {
    const bool pre = (rd + 1 < NRO);
    if (pre) {
      const int nrd = rd + 1;
      const int nstr = (nrd < RL) ? nrd : nrd - RL;
      issue(nstr * 128);
    }
    const bool lo = (rd < RL);
    round(lo ? QbL : QbH, lo ? rd : rd - RL, cur);
    if (rd == RL - 1) {
      merge_store(QbL, cur);   // scratch overlays the just-consumed buffer
      #pragma unroll
      for (int e4 = 0; e4 < 4; ++e4) acc[e4] = zero4;
      mrun = NEGBIG;
      lrun = 0.f;
      loadq(QbH);
    }
    if (pre) commit(cur ^ 1);
    __syncthreads();
    cur ^= 1;
  }

  merge_store(QbH, cur ^ 1);
}

extern "C" void kernel_launch(void* const* d_in, const int* in_sizes, int n_in,
                              void* d_out, int out_size, void* d_ws, size_t ws_size,
                              hipStream_t stream) {
  const float* Q = (const float*)d_in[0];
  const float* K = (const float*)d_in[1];
  const float* V = (const float*)d_in[2];
  float* O = (float*)d_out;
  // bf16 scratch: Kb at 0, Vt (transposed) at 8 MiB
  unsigned short* Kb = (unsigned short*)d_ws;
  unsigned short* Vt = (unsigned short*)((char*)d_ws + (size_t)Bc * Lc * Hc * Ec * 2);
  prep<<<dim3(3072), dim3(256), 0, stream>>>(K, V, (uint4*)Kb, Vt);
  dim3 grid(Bc * Hc * 16);   // 32 bh x 16 folded pairs, all identical work
  attn_fwd<<<grid, dim3(512), 0, stream>>>(Q, Kb, Vt, O);
}

// Round 17
// 61.304 us; speedup vs baseline: 1.4559x; 1.0369x over previous
//
#include <hip/hip_runtime.h>
#include <hip/hip_bf16.h>

typedef __attribute__((ext_vector_type(8))) short short8;
typedef __attribute__((ext_vector_type(4))) float f32x4;
typedef __attribute__((ext_vector_type(2))) unsigned uint2v;

#define MFMA16(a, b, c) __builtin_amdgcn_mfma_f32_16x16x32_bf16((a), (b), (c), 0, 0, 0)

constexpr int Bc = 2, Lc = 2048, Hc = 16, Ec = 64;
constexpr float LOG2E = 1.4426950408889634f;
constexpr float SCALE2 = 0.125f * LOG2E;   // fold log2(e): scores in log2 units
constexpr float NEGBIG = -3.0e38f;

union SW { short8 s8; unsigned u[4]; float4 f4; };

__device__ __forceinline__ unsigned cvtpk(float lo, float hi) {
  unsigned r;
  asm("v_cvt_pk_bf16_f32 %0, %1, %2" : "=v"(r) : "v"(lo), "v"(hi));
  return r;
}
__device__ __forceinline__ float exp2v(float x) {
  float r;
  asm("v_exp_f32 %0, %1" : "=v"(r) : "v"(x));
  return r;
}
__device__ __forceinline__ void plswap32(unsigned& a, unsigned& b) {
  uint2v r = __builtin_amdgcn_permlane32_swap(a, b, false, false);
  a = r[0]; b = r[1];
}
__device__ __forceinline__ void plswap16(unsigned& a, unsigned& b) {
  uint2v r = __builtin_amdgcn_permlane16_swap(a, b, false, false);
  a = r[0]; b = r[1];
}
__device__ __forceinline__ float bflymax(float x) {
  unsigned a = __builtin_bit_cast(unsigned, x), b = a;
  plswap16(a, b);
  float y = fmaxf(__builtin_bit_cast(float, a), __builtin_bit_cast(float, b));
  a = __builtin_bit_cast(unsigned, y); b = a;
  plswap32(a, b);
  return fmaxf(__builtin_bit_cast(float, a), __builtin_bit_cast(float, b));
}

// Fused prepass: blocks [0,2048) convert K fp32->bf16 (RNE, same as cvtpk);
// blocks [2048,3072) transpose V into chunk-major Vt[bh][s/16][e][16] bf16.
// Both reads AND writes fully coalesced (lane stride 32B on the V side).
__global__ __launch_bounds__(256)
void prep(const float* __restrict__ K, const float* __restrict__ V,
          uint4* __restrict__ Kb, unsigned short* __restrict__ Vt) {
  const int bid = blockIdx.x;
  const int t = threadIdx.x;
  if (bid < 2048) {
    const int i = bid * 256 + t;
    const float4* s = reinterpret_cast<const float4*>(K) + (size_t)i * 2;
    float4 a = s[0], b = s[1];
    uint4 o;
    o.x = cvtpk(a.x, a.y); o.y = cvtpk(a.z, a.w);
    o.z = cvtpk(b.x, b.y); o.w = cvtpk(b.z, b.w);
    Kb[i] = o;
  } else {
    const int vw = (bid - 2048) * 4 + (t >> 6);   // 0..4095 = bh*128 + chunk
    const int l = t & 63;                          // e
    const int bh = vw >> 7;                        // 0..31
    const int s0 = (vw & 127) * 16;
    const float* vp = V + ((size_t)(bh >> 4) * Lc + s0) * (Hc * Ec) +
                      (bh & 15) * Ec + l;
    float va[16];
    #pragma unroll
    for (int j = 0; j < 16; ++j) va[j] = vp[j * (Hc * Ec)];
    uint4 o0, o1;
    o0.x = cvtpk(va[0], va[1]);   o0.y = cvtpk(va[2], va[3]);
    o0.z = cvtpk(va[4], va[5]);   o0.w = cvtpk(va[6], va[7]);
    o1.x = cvtpk(va[8], va[9]);   o1.y = cvtpk(va[10], va[11]);
    o1.z = cvtpk(va[12], va[13]); o1.w = cvtpk(va[14], va[15]);
    uint4* dst = reinterpret_cast<uint4*>(Vt + ((size_t)vw * 64 + l) * 16);
    dst[0] = o0;
    dst[1] = o1;
  }
}

__global__ __launch_bounds__(512, 2)
void attn_fwd(const float* __restrict__ Qg, const unsigned short* __restrict__ Kb,
              const unsigned short* __restrict__ Vt, float* __restrict__ Og) {
  // smem (shorts), NT=128 s-tile double-buffered:
  //  kt[b]: [128][64] bf16 at b*8192, K row s at prow=pi(s), idx ^ ((prow&7)<<3)
  //  vt[b]: [64 e][128 s] bf16 at 16384 + b*8192, chunk slot = (s>>3) ^ (e&7)
  // merge scratch overlays the RETIRED buffer.
  __shared__ __align__(16) short smem[32768];

  // causal fold: block owns q-tile pair (i, 31-i): exactly 17 uniform rounds
  const int bid = blockIdx.x;
  const int pair = bid & 15;
  const int bh = bid >> 4;
  const int h = bh & (Hc - 1);
  const int b = bh >> 4;
  const int iLo = pair;
  const int QbL = iLo * 64;
  const int QbH = (31 - pair) * 64;
  const int RL = (iLo + 2) >> 1;              // lo-tile rounds; RL + RH = 17

  const int t = threadIdx.x;
  const int w = t >> 6;        // 0..7
  const int qsub = w & 3;      // q sub-block (16 rows)
  const int par = w >> 2;      // 64-s half of the 128-row tile
  const int l = t & 63;
  const int n = l & 15;
  const int g = l >> 4;
  const int sp4 = ((g & 1) << 3) | ((g >> 1) << 2);  // pi(g)*4

  const f32x4 zero4 = {0.f, 0.f, 0.f, 0.f};
  short8 onesv;
  #pragma unroll
  for (int j = 0; j < 8; ++j) onesv[j] = (short)0x3F80;  // bf16 1.0

  // Q fragments (B-operand: col=q=lane&15, k=e=(lane>>4)*8+j)
  short8 qf[2];
  auto loadq = [&](int Qb) {
    const int q = Qb + qsub * 16 + n;
    const float* qp = Qg + ((size_t)(b * Lc + q) * Hc + h) * Ec + g * 8;
    SW a0, a1, b0, b1, r0, r1;
    a0.f4 = reinterpret_cast<const float4*>(qp)[0];
    a1.f4 = reinterpret_cast<const float4*>(qp)[1];
    b0.f4 = reinterpret_cast<const float4*>(qp + 32)[0];
    b1.f4 = reinterpret_cast<const float4*>(qp + 32)[1];
    r0.u[0] = cvtpk(a0.f4.x * SCALE2, a0.f4.y * SCALE2);
    r0.u[1] = cvtpk(a0.f4.z * SCALE2, a0.f4.w * SCALE2);
    r0.u[2] = cvtpk(a1.f4.x * SCALE2, a1.f4.y * SCALE2);
    r0.u[3] = cvtpk(a1.f4.z * SCALE2, a1.f4.w * SCALE2);
    r1.u[0] = cvtpk(b0.f4.x * SCALE2, b0.f4.y * SCALE2);
    r1.u[1] = cvtpk(b0.f4.z * SCALE2, b0.f4.w * SCALE2);
    r1.u[2] = cvtpk(b1.f4.x * SCALE2, b1.f4.y * SCALE2);
    r1.u[3] = cvtpk(b1.f4.z * SCALE2, b1.f4.w * SCALE2);
    qf[0] = r0.s8;
    qf[1] = r1.s8;
  };

  // acc[e4][r] = O^T[e = e4*16 + g*4 + r][q = n]; per-lane scalar m,l
  f32x4 acc[4] = {zero4, zero4, zero4, zero4};
  float mrun = NEGBIG, lrun = 0.f;

  // staging: 512 threads stage 128 rows of K (pi-permuted) and V^T per round
  const int srow = t >> 2;                               // 0..127
  const int prow = (srow & ~12) | ((srow & 4) << 1) | ((srow & 8) >> 1);
  const int kc0 = (t & 3) * 16;                          // 16-col bf16 chunk
  const int ve = l, vs0 = w * 16;                        // V^T: e=lane, 16 s rows

  float4 kA, kB, vA, vB;   // 4 x dwordx4 bf16

  // Forced-async bf16 stage: volatile asm loads issue HERE (unsinkable).
  auto issue = [&](int r0) {
    unsigned koff = (unsigned)((((b * Lc + r0 + srow) * Hc + h) * Ec + kc0) * 2);
    // chunk-major Vt: [bh][(r0+vs0)/16][ve][16] -> 32B per lane, coalesced
    unsigned voff = (unsigned)(((bh * 128 + ((r0 + vs0) >> 4)) * 64 + ve) * 32);
    asm volatile(
      "global_load_dwordx4 %[k0], %[ko], %[kb]\n\t"
      "global_load_dwordx4 %[k1], %[ko], %[kb] offset:16\n\t"
      "global_load_dwordx4 %[v0], %[vo], %[vb]\n\t"
      "global_load_dwordx4 %[v1], %[vo], %[vb] offset:16"
      : [k0]"=v"(kA), [k1]"=v"(kB), [v0]"=v"(vA), [v1]"=v"(vB)
      : [ko]"v"(koff), [vo]"v"(voff), [kb]"s"(Kb), [vb]"s"(Vt)
      : "memory");
  };
  auto commit = [&](int buf) {
    // K first (2 V loads may remain outstanding)
    asm volatile("s_waitcnt vmcnt(2)" ::: "memory");
    __builtin_amdgcn_sched_barrier(0);
    short* kt = smem + buf * 8192;
    *reinterpret_cast<short8*>(&kt[(prow * 64 + kc0) ^ ((prow & 7) << 3)]) =
        *reinterpret_cast<short8*>(&kA);
    *reinterpret_cast<short8*>(&kt[(prow * 64 + kc0 + 8) ^ ((prow & 7) << 3)]) =
        *reinterpret_cast<short8*>(&kB);
    asm volatile("s_waitcnt vmcnt(0)" ::: "memory");
    __builtin_amdgcn_sched_barrier(0);
    short* vt = smem + 16384 + buf * 8192;
    const int ch0 = vs0 >> 3;
    *reinterpret_cast<short8*>(&vt[ve * 128 + (((ch0 + 0) ^ (ve & 7)) << 3)]) =
        *reinterpret_cast<short8*>(&vA);
    *reinterpret_cast<short8*>(&vt[ve * 128 + (((ch0 + 1) ^ (ve & 7)) << 3)]) =
        *reinterpret_cast<short8*>(&vB);
  };

  // one 64q x 128s round (this wave: 16 q x 64 s half), swapped operands
  auto round = [&](int Qb, int str, int curb) {
    const int sb = str * 128 + par * 64;
    const int qtop = Qb + qsub * 16;
    if (sb > qtop + 15) return;
    const short* ktb = smem + curb * 8192;
    const short* vtb = smem + 16384 + curb * 8192;

    // QK^T swapped: D[s][q], col = q = n; 4 cb blocks x k=64
    f32x4 sc[4] = {zero4, zero4, zero4, zero4};
    #pragma unroll
    for (int kc = 0; kc < 2; ++kc) {
      #pragma unroll
      for (int cb = 0; cb < 4; ++cb) {
        const int row = par * 64 + cb * 16 + n;
        const int idx = (row * 64 + kc * 32 + g * 8) ^ ((n & 7) << 3);
        short8 kf = *reinterpret_cast<const short8*>(&ktb[idx]);
        sc[cb] = MFMA16(kf, qf[kc], sc[cb]);
      }
    }

    const int qg = qtop + n;
    if (sb + 63 > qtop) {
      #pragma unroll
      for (int cb = 0; cb < 4; ++cb)
        #pragma unroll
        for (int r = 0; r < 4; ++r)
          if (sb + cb * 16 + sp4 + r > qg) sc[cb][r] = NEGBIG;
    }

    // row max: 15 lane-local fmax + VALU butterfly
    float m8 = fmaxf(fmaxf(fmaxf(sc[0][0], sc[0][1]), fmaxf(sc[0][2], sc[0][3])),
                     fmaxf(fmaxf(sc[1][0], sc[1][1]), fmaxf(sc[1][2], sc[1][3])));
    m8 = fmaxf(m8, fmaxf(fmaxf(fmaxf(sc[2][0], sc[2][1]), fmaxf(sc[2][2], sc[2][3])),
                         fmaxf(fmaxf(sc[3][0], sc[3][1]), fmaxf(sc[3][2], sc[3][3]))));
    m8 = bflymax(m8);

    // exact-identity rescale skip
    const bool resc = !__all(m8 <= mrun);
    if (resc) {
      const float mn = fmaxf(mrun, m8);
      const float afac = exp2v(mrun - mn);
      mrun = mn;
      lrun *= afac;
      #pragma unroll
      for (int e4 = 0; e4 < 4; ++e4)
        #pragma unroll
        for (int r = 0; r < 4; ++r) acc[e4][r] *= afac;
    }

    // P = exp2(S - m) -> packed bf16
    unsigned ua[4], ub[4];
    #pragma unroll
    for (int cb = 0; cb < 4; ++cb) {
      ua[cb] = cvtpk(exp2v(sc[cb][0] - mrun), exp2v(sc[cb][1] - mrun));
      ub[cb] = cvtpk(exp2v(sc[cb][2] - mrun), exp2v(sc[cb][3] - mrun));
    }

    // P C-frag -> B-frag: pure-VALU permlane32 swaps
    plswap32(ua[0], ua[1]);
    plswap32(ub[0], ub[1]);
    plswap32(ua[2], ua[3]);
    plswap32(ub[2], ub[3]);
    SW pw0, pw1;
    pw0.u[0] = ua[0]; pw0.u[1] = ub[0]; pw0.u[2] = ua[1]; pw0.u[3] = ub[1];
    pw1.u[0] = ua[2]; pw1.u[1] = ub[2]; pw1.u[2] = ua[3]; pw1.u[3] = ub[3];

    // PV swapped: acc = V^T x P, two k=32 slices per e-chunk
    #pragma unroll
    for (int e4 = 0; e4 < 4; ++e4) {
      const int e = e4 * 16 + n;
      const int slot0 = (par * 8 + g) ^ (e & 7);
      const int slot1 = (par * 8 + 4 + g) ^ (e & 7);
      short8 vf0 = *reinterpret_cast<const short8*>(&vtb[e * 128 + (slot0 << 3)]);
      acc[e4] = MFMA16(vf0, pw0.s8, acc[e4]);
      short8 vf1 = *reinterpret_cast<const short8*>(&vtb[e * 128 + (slot1 << 3)]);
      acc[e4] = MFMA16(vf1, pw1.s8, acc[e4]);
    }

    // row sum via ones-MFMA: D[i][q] = sum_s P[s][q], lane col q = n
    f32x4 rs = MFMA16(onesv, pw0.s8, zero4);
    rs = MFMA16(onesv, pw1.s8, rs);
    lrun += rs[0];
  };

  // merge parities via scratch overlaid on the retired buffer `curb`
  auto merge_store = [&](int Qb, int curb) {
    float* sA = reinterpret_cast<float*>(smem) + curb * 4096;         // rows 0..31
    float* sB = reinterpret_cast<float*>(smem) + 8192 + curb * 4096;  // rows 32..63 + m + l
    __syncthreads();
    const int row = qsub * 16 + n;
    if (par == 1) {
      float* base = (row < 32) ? (sA + row * 68) : (sB + (row - 32) * 68);
      #pragma unroll
      for (int e4 = 0; e4 < 4; ++e4)
        #pragma unroll
        for (int r = 0; r < 4; ++r) base[e4 * 16 + g * 4 + r] = acc[e4][r];
      if (g == 0) {
        sB[2176 + row] = mrun;
        sB[2240 + row] = lrun;
      }
    }
    __syncthreads();
    if (par == 0) {
      const float* base = (row < 32) ? (sA + row * 68) : (sB + (row - 32) * 68);
      const float m1 = sB[2176 + row];
      const float l1 = sB[2240 + row];
      const float mm = fmaxf(mrun, m1);
      const float a0 = exp2v(mrun - mm);
      const float a1 = exp2v(m1 - mm);
      const float inv = 1.0f / (lrun * a0 + l1 * a1);
      const int q = Qb + row;
      float* op = Og + ((size_t)(b * Lc + q) * Hc + h) * Ec;
      #pragma unroll
      for (int e4 = 0; e4 < 4; ++e4) {
        float4 v;
        v.x = (acc[e4][0] * a0 + base[e4 * 16 + g * 4 + 0] * a1) * inv;
        v.y = (acc[e4][1] * a0 + base[e4 * 16 + g * 4 + 1] * a1) * inv;
        v.z = (acc[e4][2] * a0 + base[e4 * 16 + g * 4 + 2] * a1) * inv;
        v.w = (acc[e4][3] * a0 + base[e4 * 16 + g * 4 + 3] * a1) * inv;
        *reinterpret_cast<float4*>(op + e4 * 16 + g * 4) = v;
      }
    }
  };

  // fused 17-round stream: rounds 0..RL-1 on tile lo, rest on tile hi
  constexpr int NRO = 17;
  loadq(QbL);
  issue(0);
  commit(0);
  __syncthreads();

  int cur = 0;
  for (int rd = 0; rd < NRO; ++rd) {
    const bool pre = (rd + 1 < NRO);
    if (pre) {
      const int nrd = rd + 1;
      const int nstr = (nrd < RL) ? nrd : nrd - RL;
      issue(nstr * 128);
    }
    const bool lo = (rd < RL);
    round(lo ? QbL : QbH, lo ? rd : rd - RL, cur);
    if (rd == RL - 1) {
      merge_store(QbL, cur);   // scratch overlays the just-consumed buffer
      #pragma unroll
      for (int e4 = 0; e4 < 4; ++e4) acc[e4] = zero4;
      mrun = NEGBIG;
      lrun = 0.f;
      loadq(QbH);
    }
    if (pre) commit(cur ^ 1);
    __syncthreads();
    cur ^= 1;
  }

  merge_store(QbH, cur ^ 1);
}

extern "C" void kernel_launch(void* const* d_in, const int* in_sizes, int n_in,
                              void* d_out, int out_size, void* d_ws, size_t ws_size,
                              hipStream_t stream) {
  const float* Q = (const float*)d_in[0];
  const float* K = (const float*)d_in[1];
  const float* V = (const float*)d_in[2];
  float* O = (float*)d_out;
  // bf16 scratch: Kb at 0, Vt (chunk-major transposed) at 8 MiB
  unsigned short* Kb = (unsigned short*)d_ws;
  unsigned short* Vt = (unsigned short*)((char*)d_ws + (size_t)Bc * Lc * Hc * Ec * 2);
  prep<<<dim3(3072), dim3(256), 0, stream>>>(K, V, (uint4*)Kb, Vt);
  dim3 grid(Bc * Hc * 16);   // 32 bh x 16 folded pairs, all identical work
  attn_fwd<<<grid, dim3(512), 0, stream>>>(Q, Kb, Vt, O);
}